// Round 3
// baseline (170.163 us; speedup 1.0000x reference)
//
#include <hip/hip_runtime.h>

typedef __attribute__((ext_vector_type(8))) short short8;
typedef __attribute__((ext_vector_type(4))) float floatx4;
typedef __attribute__((ext_vector_type(2))) unsigned int uint2v;

#define S_LEN 2048
#define D_HEAD 64
#define NT64 (S_LEN / 64)
#define PITCH 72            // fallback P pitch
#define TP 73
#define SCALE2 0.18033688f  // 0.125 * log2(e)
#define MASK_BIAS2 -2.0e9f

static __device__ __forceinline__ unsigned short f2bf(float f) {
  unsigned int x = __builtin_bit_cast(unsigned int, f);
  x += 0x7fffu + ((x >> 16) & 1u);   // RNE
  return (unsigned short)(x >> 16);
}
static __device__ __forceinline__ float bf2f(unsigned short u) {
  unsigned int x = ((unsigned int)u) << 16;
  return __builtin_bit_cast(float, x);
}
static __device__ __forceinline__ short8 cvt8(const float* __restrict__ p) {
  float4 a = *(const float4*)p;
  float4 b = *(const float4*)(p + 4);
  short8 r;
  r[0] = (short)f2bf(a.x); r[1] = (short)f2bf(a.y);
  r[2] = (short)f2bf(a.z); r[3] = (short)f2bf(a.w);
  r[4] = (short)f2bf(b.x); r[5] = (short)f2bf(b.y);
  r[6] = (short)f2bf(b.z); r[7] = (short)f2bf(b.w);
  return r;
}
// Q frag with the softmax scale folded in (bf16 rounding after scaling)
static __device__ __forceinline__ short8 cvt8s(const float* __restrict__ p) {
  float4 a = *(const float4*)p;
  float4 b = *(const float4*)(p + 4);
  short8 r;
  r[0] = (short)f2bf(a.x * SCALE2); r[1] = (short)f2bf(a.y * SCALE2);
  r[2] = (short)f2bf(a.z * SCALE2); r[3] = (short)f2bf(a.w * SCALE2);
  r[4] = (short)f2bf(b.x * SCALE2); r[5] = (short)f2bf(b.y * SCALE2);
  r[6] = (short)f2bf(b.z * SCALE2); r[7] = (short)f2bf(b.w * SCALE2);
  return r;
}
static __device__ __forceinline__ void cp16(const void* g, void* l) {
  __builtin_amdgcn_global_load_lds(
      (const __attribute__((address_space(1))) unsigned int*)g,
      (__attribute__((address_space(3))) unsigned int*)l, 16, 0, 0);
}
// fast pack: round-half-up to bf16 via +0x8000 bias, extract both hi16 with one v_perm
static __device__ __forceinline__ unsigned int pk2f(float a, float b) {
  const unsigned int ab = __builtin_bit_cast(unsigned int, a) + 0x8000u;
  const unsigned int bb = __builtin_bit_cast(unsigned int, b) + 0x8000u;
  return __builtin_amdgcn_perm(bb, ab, 0x07060302u);
}
// permlane32_swap: a's upper 32 lanes <-> b's lower 32 lanes:
//   new_a = {a[0:31], b[0:31]}, new_b = {a[32:63], b[32:63]}
static __device__ __forceinline__ void plswap32(unsigned int& a, unsigned int& b) {
#if __has_builtin(__builtin_amdgcn_permlane32_swap)
  uint2v r = __builtin_amdgcn_permlane32_swap(a, b, false, false);
  a = r[0]; b = r[1];
#else
  asm volatile("v_permlane32_swap_b32 %0, %1" : "+v"(a), "+v"(b));
#endif
}
// permlane16_swap: a's odd 16-lane rows <-> b's even rows:
//   new_a = {a0, b0, a2, b2}, new_b = {a1, b1, a3, b3}
static __device__ __forceinline__ void plswap16(unsigned int& a, unsigned int& b) {
#if __has_builtin(__builtin_amdgcn_permlane16_swap)
  uint2v r = __builtin_amdgcn_permlane16_swap(a, b, false, false);
  a = r[0]; b = r[1];
#else
  asm volatile("v_permlane16_swap_b32 %0, %1" : "+v"(a), "+v"(b));
#endif
}

// ---- fused pre-pass: K/V -> swizzled bf16 chunks, mask -> bits (c-split 4x) ----
__global__ __launch_bounds__(256) void prep(
    const float* __restrict__ K, const float* __restrict__ V,
    const int* __restrict__ mask,
    unsigned short* __restrict__ Kws, unsigned short* __restrict__ Vws,
    unsigned long long* __restrict__ Mb, int BH)
{
  __shared__ unsigned short t[D_HEAD * TP];
  const int tid = threadIdx.x;
  const int nbK = BH * 64;
  const int nbV = BH * 32;
  int b = blockIdx.x;

  if (b < nbK) {
    const int tt   = b * 256 + tid;
    const int bh   = tt >> 14;
    const int rem  = tt & 16383;
    const int tile = rem >> 9;
    const int n    = rem & 511;
    const int row  = n >> 3;
    const int col8 = (n & 7) ^ (row & 7);
    short8 r = cvt8(K + ((size_t)(bh * S_LEN + tile * 64 + row)) * D_HEAD + col8 * 8);
    *(short8*)(Kws + (size_t)tt * 8) = r;
    return;
  }
  b -= nbK;
  if (b < nbV) {
    const int tile = b & 31;
    const int bh   = b >> 5;
    const int s0   = tile * 64;
    const float* Vb = V + (size_t)bh * S_LEN * D_HEAD;
#pragma unroll
    for (int p = 0; p < 4; ++p) {
      const int s  = p * 16 + (tid >> 4);
      const int d0 = (tid & 15) * 4;
      float4 v = *(const float4*)(Vb + (size_t)(s0 + s) * D_HEAD + d0);
      unsigned short* dst = &t[s * TP + d0];
      dst[0] = f2bf(v.x); dst[1] = f2bf(v.y); dst[2] = f2bf(v.z); dst[3] = f2bf(v.w);
    }
    __syncthreads();
    unsigned short* Vo = Vws + ((size_t)(bh * 32 + tile)) * 4096;
#pragma unroll
    for (int p = 0; p < 2; ++p) {
      const int n    = p * 256 + tid;
      const int d    = n >> 3;
      const int col8 = (n & 7) ^ (d & 7);
      short8 r;
#pragma unroll
      for (int j = 0; j < 8; ++j) r[j] = (short)t[(col8 * 8 + j) * TP + d];
      *(short8*)(Vo + (size_t)n * 8) = r;
    }
    return;
  }
  b -= nbV;                              // mask: 4-row group rg, c-quarter cq
  const int rg   = b >> 2;
  const int cq   = b & 3;
  const int lane = tid & 63;
  const int row  = rg * 4 + (tid >> 6);
#pragma unroll 8
  for (int c = cq * 8; c < cq * 8 + 8; ++c) {
    const int mv = mask[(size_t)row * S_LEN + c * 64 + lane];
    const unsigned long long bm = __ballot(mv != 0);
    if (lane == 0) Mb[(size_t)row * NT64 + c] = bm;
  }
}

// ---- main: 128 q/block (32/wave), fixed-m softmax, l via ones-MFMA ----
// Round-3: P stays in registers. After QK^T, lane(quad,l16) holds
// P[k=nt*16+quad*4+r][q=l16] as words Wk[nt][r-pair]; the PV B-operand word t
// needs P[k=w*32+quad*8+2t..2t+1]. Index algebra: dest word t <- source row
// 2(quad&1)+(t>>1), word Wk[2w+(quad>>1)][t&1]. That redistribution is exactly
// permlane32_swap followed by permlane16_swap per word-pair (verified against
// the previously-passing P-LDS layout). Loop is software-pipelined:
// QK(kt+1) || softmax+PV(kt) via ping-ponged stA/stB (static indexing).
__global__ __launch_bounds__(256, 2) void fa_fwd9(
    const float* __restrict__ Q,
    const unsigned short* __restrict__ Kws,
    const unsigned short* __restrict__ Vws,
    const unsigned long long* __restrict__ Mb,
    float* __restrict__ Out)
{
  __shared__ unsigned short Kbuf[3][64 * 64];     // 8 KB each, 3-deep ring
  __shared__ unsigned short Vbuf[3][64 * 64];

  const int tid  = threadIdx.x;
  const int wv   = tid >> 6;
  const int lane = tid & 63;
  const int quad = lane >> 4;
  const int l16  = lane & 15;
  const int l8   = l16 & 7;

  // XCD-aware swizzle (nwg = 16*BH, always % 8 == 0)
  const int nwg  = gridDim.x;
  const int flat = blockIdx.x;
  const int swz  = (flat & 7) * (nwg >> 3) + (flat >> 3);
  const int bh   = swz >> 4;
  const int qw   = (swz & 15) * 128 + wv * 32;

  const float* Qb = Q + (size_t)bh * S_LEN * D_HEAD;
  const unsigned short* KT = Kws + (size_t)bh * NT64 * 4096;
  const unsigned short* VT = Vws + (size_t)bh * NT64 * 4096;

  auto stage = [&](int kt, int buf) {
#pragma unroll
    for (int j = 0; j < 2; ++j) {
      const int c0 = (wv * 2 + j) * 64;
      cp16(KT + (size_t)kt * 4096 + (size_t)(c0 + lane) * 8, &Kbuf[buf][c0 * 8]);
      cp16(VT + (size_t)kt * 4096 + (size_t)(c0 + lane) * 8, &Vbuf[buf][c0 * 8]);
    }
  };

  stage(0, 0);
  stage(1, 1);

  // Q as B-operand, scale folded in (loads overlap the staging DMA)
  short8 qfrag[2][2];
#pragma unroll
  for (int g = 0; g < 2; ++g)
#pragma unroll
    for (int w = 0; w < 2; ++w)
      qfrag[g][w] = cvt8s(Qb + (size_t)(qw + g * 16 + l16) * D_HEAD + w * 32 + quad * 8);

  short8 kones;
#pragma unroll
  for (int j = 0; j < 8; ++j) kones[j] = (short)0x3F80;

  floatx4 ot[2][4];
#pragma unroll
  for (int g = 0; g < 2; ++g)
#pragma unroll
    for (int dt = 0; dt < 4; ++dt) ot[g][dt] = (floatx4){0.f, 0.f, 0.f, 0.f};
  floatx4 lacc[2];
  lacc[0] = (floatx4){0.f, 0.f, 0.f, 0.f};
  lacc[1] = (floatx4){0.f, 0.f, 0.f, 0.f};

  const unsigned long long* mrowp[2];
#pragma unroll
  for (int g = 0; g < 2; ++g)
    mrowp[g] = Mb + (size_t)(qw + g * 16 + l16) * NT64;

  floatx4 stA[2][4], stB[2][4];

  // S^T(tile) = K (Q*scale)^T into sdst
  auto qk = [&](floatx4 (&sdst)[2][4], const unsigned short* Kl) {
#pragma unroll
    for (int g = 0; g < 2; ++g)
#pragma unroll
      for (int nt = 0; nt < 4; ++nt) sdst[g][nt] = (floatx4){0.f, 0.f, 0.f, 0.f};
    __builtin_amdgcn_s_setprio(1);
#pragma unroll
    for (int w = 0; w < 2; ++w)
#pragma unroll
      for (int nt = 0; nt < 4; ++nt) {
        short8 kf = *(const short8*)&Kl[(nt * 16 + l16) * 64 + (((w * 4 + quad) ^ l8) * 8)];
        sdst[0][nt] = __builtin_amdgcn_mfma_f32_16x16x32_bf16(kf, qfrag[0][w], sdst[0][nt], 0, 0, 0);
        sdst[1][nt] = __builtin_amdgcn_mfma_f32_16x16x32_bf16(kf, qfrag[1][w], sdst[1][nt], 0, 0, 0);
      }
    __builtin_amdgcn_s_setprio(0);
  };

  // softmax(scur) -> in-register P fragments (double permlane swap), then
  // O^T += V^T P^T and l += ones * P^T
  auto sm_pv = [&](floatx4 (&scur)[2][4], const int kt, const unsigned short* Vl) {
    short8 pf[2][2];
#pragma unroll
    for (int g = 0; g < 2; ++g) {
      const unsigned long long mw = mrowp[g][kt];
      unsigned int Wk[4][2];
#pragma unroll
      for (int nt = 0; nt < 4; ++nt) {
        const unsigned nib = (unsigned)(mw >> (nt * 16 + quad * 4)) & 0xFu;
        float p[4];
#pragma unroll
        for (int r = 0; r < 4; ++r) {
          float pv = __builtin_amdgcn_exp2f(scur[g][nt][r]);
          p[r] = ((nib >> r) & 1u) ? 0.0f : pv;
        }
        Wk[nt][0] = pk2f(p[0], p[1]);
        Wk[nt][1] = pk2f(p[2], p[3]);
      }
#pragma unroll
      for (int w = 0; w < 2; ++w) {
        // A = Wk[2w][d] (rows for quad 0/1), B = Wk[2w+1][d] (rows for quad 2/3)
        unsigned a0 = Wk[2 * w][0], b0 = Wk[2 * w + 1][0];
        plswap32(a0, b0);       // a0={A0,A1,B0,B1}, b0={A2,A3,B2,B3}
        plswap16(a0, b0);       // a0=W0={A0,A2,B0,B2}, b0=W2={A1,A3,B1,B3}
        unsigned a1 = Wk[2 * w][1], b1 = Wk[2 * w + 1][1];
        plswap32(a1, b1);
        plswap16(a1, b1);       // a1=W1, b1=W3
        uint4 wd;
        wd.x = a0; wd.y = a1; wd.z = b0; wd.w = b1;
        pf[g][w] = __builtin_bit_cast(short8, wd);
      }
    }
    __builtin_amdgcn_s_setprio(1);
#pragma unroll
    for (int w = 0; w < 2; ++w) {
      lacc[0] = __builtin_amdgcn_mfma_f32_16x16x32_bf16(kones, pf[0][w], lacc[0], 0, 0, 0);
      lacc[1] = __builtin_amdgcn_mfma_f32_16x16x32_bf16(kones, pf[1][w], lacc[1], 0, 0, 0);
#pragma unroll
      for (int dt = 0; dt < 4; ++dt) {
        short8 vf = *(const short8*)&Vl[(dt * 16 + l16) * 64 + (((w * 4 + quad) ^ l8) * 8)];
        ot[0][dt] = __builtin_amdgcn_mfma_f32_16x16x32_bf16(vf, pf[0][w], ot[0][dt], 0, 0, 0);
        ot[1][dt] = __builtin_amdgcn_mfma_f32_16x16x32_bf16(vf, pf[1][w], ot[1][dt], 0, 0, 0);
      }
    }
    __builtin_amdgcn_s_setprio(0);
  };

  // pipelined body: wait tile kt+1's DMA, barrier (everyone done reading the
  // buffer stage() will overwrite), prefetch kt+2, QK(kt+1) || softmax+PV(kt)
  auto body = [&](floatx4 (&scur)[2][4], floatx4 (&snxt)[2][4],
                  const int kt, const int bV, const int bKn, const int bS) {
    asm volatile("s_waitcnt vmcnt(0)" ::: "memory");
    __builtin_amdgcn_s_barrier();
    if (kt + 2 < NT64) stage(kt + 2, bS);
    qk(snxt, Kbuf[bKn]);
    sm_pv(scur, kt, Vbuf[bV]);
  };

  // prologue: tiles 0,1 staged; wait all (incl. Q loads), compute QK(0)
  asm volatile("s_waitcnt vmcnt(0)" ::: "memory");
  __builtin_amdgcn_s_barrier();
  qk(stA, Kbuf[0]);

  int bV = 0, bKn = 1, bS = 2;
  for (int kt = 0; kt < NT64 - 2; kt += 2) {
    body(stA, stB, kt, bV, bKn, bS);
    { const int t = bV; bV = bKn; bKn = bS; bS = t; }
    body(stB, stA, kt + 1, bV, bKn, bS);
    { const int t = bV; bV = bKn; bKn = bS; bS = t; }
  }
  body(stA, stB, NT64 - 2, bV, bKn, bS);
  { const int t = bV; bV = bKn; bKn = bS; bS = t; }
  // tail: tile NT64-1 (its V buffer is staged and cannot be overwritten)
  sm_pv(stB, NT64 - 1, Vbuf[bV]);

  // ---- epilogue: l fully reduced by ones-MFMA; store O = O^T^T / l ----
#pragma unroll
  for (int g = 0; g < 2; ++g) {
    const float invl = 1.0f / lacc[g][0];
    float* Ob = Out + (size_t)bh * S_LEN * D_HEAD + (size_t)(qw + g * 16 + l16) * D_HEAD;
#pragma unroll
    for (int dt = 0; dt < 4; ++dt) {
      float4 v;
      v.x = ot[g][dt][0] * invl; v.y = ot[g][dt][1] * invl;
      v.z = ot[g][dt][2] * invl; v.w = ot[g][dt][3] * invl;
      *(float4*)(Ob + dt * 16 + quad * 4) = v;
    }
  }
}

// ---- fallback (round-6 verified) for small ws ----
__global__ __launch_bounds__(256) void fa_fwd(
    const float* __restrict__ Q, const float* __restrict__ K, const float* __restrict__ V,
    const int* __restrict__ mask, float* __restrict__ Out)
{
  __shared__ unsigned short Vt[D_HEAD * PITCH];
  __shared__ unsigned short Plds[4][16 * PITCH];
  const int tid = threadIdx.x, wv = tid >> 6, lane = tid & 63, quad = lane >> 4, l16 = lane & 15;
  const int bh = blockIdx.y, qw = blockIdx.x * 64 + wv * 16;
  const float* Qb = Q + (size_t)bh * S_LEN * D_HEAD;
  const float* Kb = K + (size_t)bh * S_LEN * D_HEAD;
  const float* Vb = V + (size_t)bh * S_LEN * D_HEAD;
  short8 qfrag[2];
#pragma unroll
  for (int w = 0; w < 2; ++w)
    qfrag[w] = cvt8(Qb + (size_t)(qw + l16) * D_HEAD + w * 32 + quad * 8);
  floatx4 o[4];
#pragma unroll
  for (int nt = 0; nt < 4; ++nt) o[nt] = (floatx4){0.f, 0.f, 0.f, 0.f};
  float m_run[4], l_run[4];
#pragma unroll
  for (int r = 0; r < 4; ++r) { m_run[r] = -1.0e30f; l_run[r] = 0.f; }
  unsigned short* pl = &Plds[wv][0];
  for (int kt = 0; kt < NT64; ++kt) {
    const int k0 = kt * 64;
    __syncthreads();
#pragma unroll
    for (int it = 0; it < 2; ++it) {
      const int s = it * 32 + (tid >> 3), d0 = (tid & 7) * 8, dblk = (tid & 7);
      const int swz = (((s >> 3) ^ dblk) & 7) * 8 + (s & 7);
      const float* vp = Vb + (size_t)(k0 + s) * D_HEAD + d0;
      float4 a = *(const float4*)vp; float4 bb = *(const float4*)(vp + 4);
      const float vvv[8] = {a.x, a.y, a.z, a.w, bb.x, bb.y, bb.z, bb.w};
#pragma unroll
      for (int j = 0; j < 8; ++j) Vt[(d0 + j) * PITCH + swz] = f2bf(vvv[j]);
    }
    __syncthreads();
    floatx4 scf[4];
#pragma unroll
    for (int nt = 0; nt < 4; ++nt) scf[nt] = (floatx4){0.f, 0.f, 0.f, 0.f};
#pragma unroll
    for (int w = 0; w < 2; ++w)
#pragma unroll
      for (int nt = 0; nt < 4; ++nt) {
        short8 kf = cvt8(Kb + (size_t)(k0 + nt * 16 + l16) * D_HEAD + w * 32 + quad * 8);
        scf[nt] = __builtin_amdgcn_mfma_f32_16x16x32_bf16(qfrag[w], kf, scf[nt], 0, 0, 0);
      }
    float s_val[4][4], mloc[4] = {-1.0e30f, -1.0e30f, -1.0e30f, -1.0e30f};
#pragma unroll
    for (int nt = 0; nt < 4; ++nt)
#pragma unroll
      for (int r = 0; r < 4; ++r) {
        const int mk = mask[(size_t)(qw + quad * 4 + r) * S_LEN + (k0 + nt * 16 + l16)];
        const float sv = scf[nt][r] * SCALE2 + (mk ? MASK_BIAS2 : 0.0f);
        s_val[nt][r] = sv; mloc[r] = fmaxf(mloc[r], sv);
      }
#pragma unroll
    for (int r = 0; r < 4; ++r)
#pragma unroll
      for (int off = 1; off < 16; off <<= 1) mloc[r] = fmaxf(mloc[r], __shfl_xor(mloc[r], off));
    float alpha[4], rsum[4];
#pragma unroll
    for (int r = 0; r < 4; ++r) {
      const float mnew = fmaxf(m_run[r], mloc[r]);
      alpha[r] = exp2f(m_run[r] - mnew); m_run[r] = mnew; rsum[r] = 0.f;
    }
#pragma unroll
    for (int nt = 0; nt < 4; ++nt)
#pragma unroll
      for (int r = 0; r < 4; ++r) {
        const float p = exp2f(s_val[nt][r] - m_run[r]);
        const unsigned short ph = f2bf(p);
        rsum[r] += bf2f(ph);
        pl[(quad * 4 + r) * PITCH + nt * 16 + l16] = ph;
      }
    __syncthreads();
#pragma unroll
    for (int r = 0; r < 4; ++r) {
#pragma unroll
      for (int off = 1; off < 16; off <<= 1) rsum[r] += __shfl_xor(rsum[r], off);
      l_run[r] = l_run[r] * alpha[r] + rsum[r];
    }
#pragma unroll
    for (int nt = 0; nt < 4; ++nt)
#pragma unroll
      for (int r = 0; r < 4; ++r) o[nt][r] *= alpha[r];
#pragma unroll
    for (int w = 0; w < 2; ++w) {
      short8 af = *(const short8*)&pl[l16 * PITCH + w * 32 + quad * 8];
#pragma unroll
      for (int nt = 0; nt < 4; ++nt) {
        const int d = nt * 16 + l16, blk = ((w * 4 + quad) ^ (d >> 3)) & 7;
        short8 vf = *(const short8*)&Vt[d * PITCH + blk * 8];
        o[nt] = __builtin_amdgcn_mfma_f32_16x16x32_bf16(af, vf, o[nt], 0, 0, 0);
      }
    }
  }
  float invl[4];
#pragma unroll
  for (int r = 0; r < 4; ++r) invl[r] = 1.0f / l_run[r];
  float* Ob = Out + (size_t)bh * S_LEN * D_HEAD;
#pragma unroll
  for (int nt = 0; nt < 4; ++nt)
#pragma unroll
    for (int r = 0; r < 4; ++r)
      Ob[(size_t)(qw + quad * 4 + r) * D_HEAD + nt * 16 + l16] = o[nt][r] * invl[r];
}

extern "C" void kernel_launch(void* const* d_in, const int* in_sizes, int n_in,
                              void* d_out, int out_size, void* d_ws, size_t ws_size,
                              hipStream_t stream) {
  const float* Q = (const float*)d_in[0];
  const float* K = (const float*)d_in[1];
  const float* V = (const float*)d_in[2];
  const int* mask = (const int*)d_in[3];
  float* Out = (float*)d_out;
  const int BH = in_sizes[0] / (S_LEN * D_HEAD);
  const size_t NH = (size_t)BH * S_LEN * D_HEAD;
  const size_t nMb = (size_t)S_LEN * NT64;
  const size_t need = NH * 2 * 2 + nMb * 8;

  if (ws_size >= need) {
    unsigned short* Kws = (unsigned short*)d_ws;
    unsigned short* Vws = Kws + NH;
    unsigned long long* Mbits = (unsigned long long*)(Vws + NH);
    const int nbPrep = BH * 64 + BH * 32 + S_LEN;   // K-cvt + V-transpose + mask (4x c-split)
    prep<<<dim3(nbPrep), 256, 0, stream>>>(K, V, mask, Kws, Vws, Mbits, BH);
    fa_fwd9<<<dim3((S_LEN / 128) * BH), 256, 0, stream>>>(Q, Kws, Vws, Mbits, Out);
  } else {
    fa_fwd<<<dim3(S_LEN / 64, BH), 256, 0, stream>>>(Q, K, V, mask, Out);
  }
}

// Round 4
// 162.876 us; speedup vs baseline: 1.0447x; 1.0447x over previous
//
#include <hip/hip_runtime.h>

typedef __attribute__((ext_vector_type(8))) short short8;
typedef __attribute__((ext_vector_type(4))) float floatx4;
typedef __attribute__((ext_vector_type(2))) unsigned int uint2v;

#define S_LEN 2048
#define D_HEAD 64
#define NT64 (S_LEN / 64)
#define PITCH 72            // fallback P pitch
#define TP 73
#define SCALE2 0.18033688f  // 0.125 * log2(e)
#define MASK_BIAS2 -2.0e9f

static __device__ __forceinline__ unsigned short f2bf(float f) {
  unsigned int x = __builtin_bit_cast(unsigned int, f);
  x += 0x7fffu + ((x >> 16) & 1u);   // RNE
  return (unsigned short)(x >> 16);
}
static __device__ __forceinline__ float bf2f(unsigned short u) {
  unsigned int x = ((unsigned int)u) << 16;
  return __builtin_bit_cast(float, x);
}
static __device__ __forceinline__ short8 cvt8(const float* __restrict__ p) {
  float4 a = *(const float4*)p;
  float4 b = *(const float4*)(p + 4);
  short8 r;
  r[0] = (short)f2bf(a.x); r[1] = (short)f2bf(a.y);
  r[2] = (short)f2bf(a.z); r[3] = (short)f2bf(a.w);
  r[4] = (short)f2bf(b.x); r[5] = (short)f2bf(b.y);
  r[6] = (short)f2bf(b.z); r[7] = (short)f2bf(b.w);
  return r;
}
// Q frag with the softmax scale folded in (bf16 rounding after scaling)
static __device__ __forceinline__ short8 cvt8s(const float* __restrict__ p) {
  float4 a = *(const float4*)p;
  float4 b = *(const float4*)(p + 4);
  short8 r;
  r[0] = (short)f2bf(a.x * SCALE2); r[1] = (short)f2bf(a.y * SCALE2);
  r[2] = (short)f2bf(a.z * SCALE2); r[3] = (short)f2bf(a.w * SCALE2);
  r[4] = (short)f2bf(b.x * SCALE2); r[5] = (short)f2bf(b.y * SCALE2);
  r[6] = (short)f2bf(b.z * SCALE2); r[7] = (short)f2bf(b.w * SCALE2);
  return r;
}
static __device__ __forceinline__ void cp16(const void* g, void* l) {
  __builtin_amdgcn_global_load_lds(
      (const __attribute__((address_space(1))) unsigned int*)g,
      (__attribute__((address_space(3))) unsigned int*)l, 16, 0, 0);
}
// fast pack: round-half-up to bf16 via +0x8000 bias, extract both hi16 with one v_perm
static __device__ __forceinline__ unsigned int pk2f(float a, float b) {
  const unsigned int ab = __builtin_bit_cast(unsigned int, a) + 0x8000u;
  const unsigned int bb = __builtin_bit_cast(unsigned int, b) + 0x8000u;
  return __builtin_amdgcn_perm(bb, ab, 0x07060302u);
}
// permlane32_swap: a's upper 32 lanes <-> b's lower 32 lanes
static __device__ __forceinline__ void plswap32(unsigned int& a, unsigned int& b) {
#if __has_builtin(__builtin_amdgcn_permlane32_swap)
  uint2v r = __builtin_amdgcn_permlane32_swap(a, b, false, false);
  a = r[0]; b = r[1];
#else
  asm volatile("v_permlane32_swap_b32 %0, %1" : "+v"(a), "+v"(b));
#endif
}
// permlane16_swap: a's odd 16-lane rows <-> b's even rows
static __device__ __forceinline__ void plswap16(unsigned int& a, unsigned int& b) {
#if __has_builtin(__builtin_amdgcn_permlane16_swap)
  uint2v r = __builtin_amdgcn_permlane16_swap(a, b, false, false);
  a = r[0]; b = r[1];
#else
  asm volatile("v_permlane16_swap_b32 %0, %1" : "+v"(a), "+v"(b));
#endif
}

// ---- fused pre-pass: K/V -> swizzled bf16 chunks, mask -> bits (c-split 4x) ----
__global__ __launch_bounds__(256) void prep(
    const float* __restrict__ K, const float* __restrict__ V,
    const int* __restrict__ mask,
    unsigned short* __restrict__ Kws, unsigned short* __restrict__ Vws,
    unsigned long long* __restrict__ Mb, int BH)
{
  __shared__ unsigned short t[D_HEAD * TP];
  const int tid = threadIdx.x;
  const int nbK = BH * 64;
  const int nbV = BH * 32;
  int b = blockIdx.x;

  if (b < nbK) {
    const int tt   = b * 256 + tid;
    const int bh   = tt >> 14;
    const int rem  = tt & 16383;
    const int tile = rem >> 9;
    const int n    = rem & 511;
    const int row  = n >> 3;
    const int col8 = (n & 7) ^ (row & 7);
    short8 r = cvt8(K + ((size_t)(bh * S_LEN + tile * 64 + row)) * D_HEAD + col8 * 8);
    *(short8*)(Kws + (size_t)tt * 8) = r;
    return;
  }
  b -= nbK;
  if (b < nbV) {
    const int tile = b & 31;
    const int bh   = b >> 5;
    const int s0   = tile * 64;
    const float* Vb = V + (size_t)bh * S_LEN * D_HEAD;
#pragma unroll
    for (int p = 0; p < 4; ++p) {
      const int s  = p * 16 + (tid >> 4);
      const int d0 = (tid & 15) * 4;
      float4 v = *(const float4*)(Vb + (size_t)(s0 + s) * D_HEAD + d0);
      unsigned short* dst = &t[s * TP + d0];
      dst[0] = f2bf(v.x); dst[1] = f2bf(v.y); dst[2] = f2bf(v.z); dst[3] = f2bf(v.w);
    }
    __syncthreads();
    unsigned short* Vo = Vws + ((size_t)(bh * 32 + tile)) * 4096;
#pragma unroll
    for (int p = 0; p < 2; ++p) {
      const int n    = p * 256 + tid;
      const int d    = n >> 3;
      const int col8 = (n & 7) ^ (d & 7);
      short8 r;
#pragma unroll
      for (int j = 0; j < 8; ++j) r[j] = (short)t[(col8 * 8 + j) * TP + d];
      *(short8*)(Vo + (size_t)n * 8) = r;
    }
    return;
  }
  b -= nbV;                              // mask: 4-row group rg, c-quarter cq
  const int rg   = b >> 2;
  const int cq   = b & 3;
  const int lane = tid & 63;
  const int row  = rg * 4 + (tid >> 6);
#pragma unroll 8
  for (int c = cq * 8; c < cq * 8 + 8; ++c) {
    const int mv = mask[(size_t)row * S_LEN + c * 64 + lane];
    const unsigned long long bm = __ballot(mv != 0);
    if (lane == 0) Mb[(size_t)row * NT64 + c] = bm;
  }
}

// ---- main: 64 q/block, 16 q/wave, fixed-m softmax, l via ones-MFMA ----
// Round-4: occupancy attack. Three rounds of structural changes (L2 swizzle,
// counted vmcnt, in-register P) all landed at ~76 us with Occupancy 18%,
// VALU 42%, Mfma 20%, idle 38% -- the invariant was grid 512 = 2 blocks/CU
// = 2 waves/SIMD, too little TLP to hide dependent-chain latency. Halve the
// per-wave tile (16 q/wave) -> grid 1024 = 4 blocks/CU exactly; 2-deep LDS
// ring (32 KB) and __launch_bounds__(256,4) keep 4 blocks resident ->
// 4 waves/SIMD. MFMA count conserved; per-wave VALU halves, wave count
// doubles; the idle 38% gets filled by cross-wave overlap.
__global__ __launch_bounds__(256, 4) void fa_fwd10(
    const float* __restrict__ Q,
    const unsigned short* __restrict__ Kws,
    const unsigned short* __restrict__ Vws,
    const unsigned long long* __restrict__ Mb,
    float* __restrict__ Out)
{
  __shared__ unsigned short Kbuf[2][64 * 64];     // 8 KB each, double buffer
  __shared__ unsigned short Vbuf[2][64 * 64];

  const int tid  = threadIdx.x;
  const int wv   = tid >> 6;
  const int lane = tid & 63;
  const int quad = lane >> 4;
  const int l16  = lane & 15;
  const int l8   = l16 & 7;

  // XCD-aware swizzle (nwg = 32*BH, % 8 == 0): each XCD owns 4 complete bh
  const int nwg  = gridDim.x;
  const int flat = blockIdx.x;
  const int swz  = (flat & 7) * (nwg >> 3) + (flat >> 3);
  const int bh   = swz >> 5;                      // 32 q-chunks per bh
  const int qw   = (swz & 31) * 64 + wv * 16;     // this wave's 16 q-rows

  const float* Qb = Q + (size_t)bh * S_LEN * D_HEAD;
  const unsigned short* KT = Kws + (size_t)bh * NT64 * 4096;
  const unsigned short* VT = Vws + (size_t)bh * NT64 * 4096;

  auto stage = [&](int kt, int buf) {
#pragma unroll
    for (int j = 0; j < 2; ++j) {
      const int c0 = (wv * 2 + j) * 64;
      cp16(KT + (size_t)kt * 4096 + (size_t)(c0 + lane) * 8, &Kbuf[buf][c0 * 8]);
      cp16(VT + (size_t)kt * 4096 + (size_t)(c0 + lane) * 8, &Vbuf[buf][c0 * 8]);
    }
  };

  stage(0, 0);

  // Q as B-operand (16 q-columns), scale folded in; overlaps the staging DMA
  short8 qfrag[2];
#pragma unroll
  for (int w = 0; w < 2; ++w)
    qfrag[w] = cvt8s(Qb + (size_t)(qw + l16) * D_HEAD + w * 32 + quad * 8);

  short8 kones;
#pragma unroll
  for (int j = 0; j < 8; ++j) kones[j] = (short)0x3F80;

  floatx4 ot[4];      // O^T: row d = dt*16+quad*4+r, col q = l16
#pragma unroll
  for (int dt = 0; dt < 4; ++dt) ot[dt] = (floatx4){0.f, 0.f, 0.f, 0.f};
  floatx4 lacc = (floatx4){0.f, 0.f, 0.f, 0.f};

  const unsigned long long* mrow = Mb + (size_t)(qw + l16) * NT64;

  __syncthreads();    // stage(0) complete (vmcnt0 drain) before first reads

  for (int kt = 0; kt < NT64; ++kt) {
    const int cur = kt & 1;
    if (kt + 1 < NT64) stage(kt + 1, cur ^ 1);
    const unsigned short* Kl = Kbuf[cur];
    const unsigned short* Vl = Vbuf[cur];

    // ---- S^T = K (Q*scale)^T ----
    floatx4 st[4];
#pragma unroll
    for (int nt = 0; nt < 4; ++nt) st[nt] = (floatx4){0.f, 0.f, 0.f, 0.f};
    __builtin_amdgcn_s_setprio(1);
#pragma unroll
    for (int w = 0; w < 2; ++w)
#pragma unroll
      for (int nt = 0; nt < 4; ++nt) {
        short8 kf = *(const short8*)&Kl[(nt * 16 + l16) * 64 + (((w * 4 + quad) ^ l8) * 8)];
        st[nt] = __builtin_amdgcn_mfma_f32_16x16x32_bf16(kf, qfrag[w], st[nt], 0, 0, 0);
      }
    __builtin_amdgcn_s_setprio(0);

    // ---- p = exp2(st), zero masked, pack; P->B-operand via permlane swaps ----
    const unsigned long long mw = mrow[kt];
    unsigned int Wk[4][2];
#pragma unroll
    for (int nt = 0; nt < 4; ++nt) {
      const unsigned nib = (unsigned)(mw >> (nt * 16 + quad * 4)) & 0xFu;
      float p[4];
#pragma unroll
      for (int r = 0; r < 4; ++r) {
        float pv = __builtin_amdgcn_exp2f(st[nt][r]);
        p[r] = ((nib >> r) & 1u) ? 0.0f : pv;
      }
      Wk[nt][0] = pk2f(p[0], p[1]);
      Wk[nt][1] = pk2f(p[2], p[3]);
    }
    short8 pf[2];
#pragma unroll
    for (int w = 0; w < 2; ++w) {
      unsigned a0 = Wk[2 * w][0], b0 = Wk[2 * w + 1][0];
      plswap32(a0, b0);       // a0={A0,A1,B0,B1}, b0={A2,A3,B2,B3}
      plswap16(a0, b0);       // a0=W0={A0,A2,B0,B2}, b0=W2={A1,A3,B1,B3}
      unsigned a1 = Wk[2 * w][1], b1 = Wk[2 * w + 1][1];
      plswap32(a1, b1);
      plswap16(a1, b1);       // a1=W1, b1=W3
      uint4 wd;
      wd.x = a0; wd.y = a1; wd.z = b0; wd.w = b1;
      pf[w] = __builtin_bit_cast(short8, wd);
    }

    // ---- O^T += V^T P^T ; l += ones * P^T ----
    __builtin_amdgcn_s_setprio(1);
#pragma unroll
    for (int w = 0; w < 2; ++w) {
      lacc = __builtin_amdgcn_mfma_f32_16x16x32_bf16(kones, pf[w], lacc, 0, 0, 0);
#pragma unroll
      for (int dt = 0; dt < 4; ++dt) {
        short8 vf = *(const short8*)&Vl[(dt * 16 + l16) * 64 + (((w * 4 + quad) ^ l8) * 8)];
        ot[dt] = __builtin_amdgcn_mfma_f32_16x16x32_bf16(vf, pf[w], ot[dt], 0, 0, 0);
      }
    }
    __builtin_amdgcn_s_setprio(0);

    // drain stage(kt+1) (issued a full iteration ago -> cheap) + buffer swap
    __syncthreads();
  }

  // ---- epilogue: l fully reduced by ones-MFMA; store O = O^T^T / l ----
  const float invl = 1.0f / lacc[0];
  float* Ob = Out + (size_t)bh * S_LEN * D_HEAD + (size_t)(qw + l16) * D_HEAD;
#pragma unroll
  for (int dt = 0; dt < 4; ++dt) {
    float4 v;
    v.x = ot[dt][0] * invl; v.y = ot[dt][1] * invl;
    v.z = ot[dt][2] * invl; v.w = ot[dt][3] * invl;
    *(float4*)(Ob + dt * 16 + quad * 4) = v;
  }
}

// ---- fallback (round-6 verified) for small ws ----
__global__ __launch_bounds__(256) void fa_fwd(
    const float* __restrict__ Q, const float* __restrict__ K, const float* __restrict__ V,
    const int* __restrict__ mask, float* __restrict__ Out)
{
  __shared__ unsigned short Vt[D_HEAD * PITCH];
  __shared__ unsigned short Plds[4][16 * PITCH];
  const int tid = threadIdx.x, wv = tid >> 6, lane = tid & 63, quad = lane >> 4, l16 = lane & 15;
  const int bh = blockIdx.y, qw = blockIdx.x * 64 + wv * 16;
  const float* Qb = Q + (size_t)bh * S_LEN * D_HEAD;
  const float* Kb = K + (size_t)bh * S_LEN * D_HEAD;
  const float* Vb = V + (size_t)bh * S_LEN * D_HEAD;
  short8 qfrag[2];
#pragma unroll
  for (int w = 0; w < 2; ++w)
    qfrag[w] = cvt8(Qb + (size_t)(qw + l16) * D_HEAD + w * 32 + quad * 8);
  floatx4 o[4];
#pragma unroll
  for (int nt = 0; nt < 4; ++nt) o[nt] = (floatx4){0.f, 0.f, 0.f, 0.f};
  float m_run[4], l_run[4];
#pragma unroll
  for (int r = 0; r < 4; ++r) { m_run[r] = -1.0e30f; l_run[r] = 0.f; }
  unsigned short* pl = &Plds[wv][0];
  for (int kt = 0; kt < NT64; ++kt) {
    const int k0 = kt * 64;
    __syncthreads();
#pragma unroll
    for (int it = 0; it < 2; ++it) {
      const int s = it * 32 + (tid >> 3), d0 = (tid & 7) * 8, dblk = (tid & 7);
      const int swz = (((s >> 3) ^ dblk) & 7) * 8 + (s & 7);
      const float* vp = Vb + (size_t)(k0 + s) * D_HEAD + d0;
      float4 a = *(const float4*)vp; float4 bb = *(const float4*)(vp + 4);
      const float vvv[8] = {a.x, a.y, a.z, a.w, bb.x, bb.y, bb.z, bb.w};
#pragma unroll
      for (int j = 0; j < 8; ++j) Vt[(d0 + j) * PITCH + swz] = f2bf(vvv[j]);
    }
    __syncthreads();
    floatx4 scf[4];
#pragma unroll
    for (int nt = 0; nt < 4; ++nt) scf[nt] = (floatx4){0.f, 0.f, 0.f, 0.f};
#pragma unroll
    for (int w = 0; w < 2; ++w)
#pragma unroll
      for (int nt = 0; nt < 4; ++nt) {
        short8 kf = cvt8(Kb + (size_t)(k0 + nt * 16 + l16) * D_HEAD + w * 32 + quad * 8);
        scf[nt] = __builtin_amdgcn_mfma_f32_16x16x32_bf16(qfrag[w], kf, scf[nt], 0, 0, 0);
      }
    float s_val[4][4], mloc[4] = {-1.0e30f, -1.0e30f, -1.0e30f, -1.0e30f};
#pragma unroll
    for (int nt = 0; nt < 4; ++nt)
#pragma unroll
      for (int r = 0; r < 4; ++r) {
        const int mk = mask[(size_t)(qw + quad * 4 + r) * S_LEN + (k0 + nt * 16 + l16)];
        const float sv = scf[nt][r] * SCALE2 + (mk ? MASK_BIAS2 : 0.0f);
        s_val[nt][r] = sv; mloc[r] = fmaxf(mloc[r], sv);
      }
#pragma unroll
    for (int r = 0; r < 4; ++r)
#pragma unroll
      for (int off = 1; off < 16; off <<= 1) mloc[r] = fmaxf(mloc[r], __shfl_xor(mloc[r], off));
    float alpha[4], rsum[4];
#pragma unroll
    for (int r = 0; r < 4; ++r) {
      const float mnew = fmaxf(m_run[r], mloc[r]);
      alpha[r] = exp2f(m_run[r] - mnew); m_run[r] = mnew; rsum[r] = 0.f;
    }
#pragma unroll
    for (int nt = 0; nt < 4; ++nt)
#pragma unroll
      for (int r = 0; r < 4; ++r) {
        const float p = exp2f(s_val[nt][r] - m_run[r]);
        const unsigned short ph = f2bf(p);
        rsum[r] += bf2f(ph);
        pl[(quad * 4 + r) * PITCH + nt * 16 + l16] = ph;
      }
    __syncthreads();
#pragma unroll
    for (int r = 0; r < 4; ++r) {
#pragma unroll
      for (int off = 1; off < 16; off <<= 1) rsum[r] += __shfl_xor(rsum[r], off);
      l_run[r] = l_run[r] * alpha[r] + rsum[r];
    }
#pragma unroll
    for (int nt = 0; nt < 4; ++nt)
#pragma unroll
      for (int r = 0; r < 4; ++r) o[nt][r] *= alpha[r];
#pragma unroll
    for (int w = 0; w < 2; ++w) {
      short8 af = *(const short8*)&pl[l16 * PITCH + w * 32 + quad * 8];
#pragma unroll
      for (int nt = 0; nt < 4; ++nt) {
        const int d = nt * 16 + l16, blk = ((w * 4 + quad) ^ (d >> 3)) & 7;
        short8 vf = *(const short8*)&Vt[d * PITCH + blk * 8];
        o[nt] = __builtin_amdgcn_mfma_f32_16x16x32_bf16(af, vf, o[nt], 0, 0, 0);
      }
    }
  }
  float invl[4];
#pragma unroll
  for (int r = 0; r < 4; ++r) invl[r] = 1.0f / l_run[r];
  float* Ob = Out + (size_t)bh * S_LEN * D_HEAD;
#pragma unroll
  for (int nt = 0; nt < 4; ++nt)
#pragma unroll
    for (int r = 0; r < 4; ++r)
      Ob[(size_t)(qw + quad * 4 + r) * D_HEAD + nt * 16 + l16] = o[nt][r] * invl[r];
}

extern "C" void kernel_launch(void* const* d_in, const int* in_sizes, int n_in,
                              void* d_out, int out_size, void* d_ws, size_t ws_size,
                              hipStream_t stream) {
  const float* Q = (const float*)d_in[0];
  const float* K = (const float*)d_in[1];
  const float* V = (const float*)d_in[2];
  const int* mask = (const int*)d_in[3];
  float* Out = (float*)d_out;
  const int BH = in_sizes[0] / (S_LEN * D_HEAD);
  const size_t NH = (size_t)BH * S_LEN * D_HEAD;
  const size_t nMb = (size_t)S_LEN * NT64;
  const size_t need = NH * 2 * 2 + nMb * 8;

  if (ws_size >= need) {
    unsigned short* Kws = (unsigned short*)d_ws;
    unsigned short* Vws = Kws + NH;
    unsigned long long* Mbits = (unsigned long long*)(Vws + NH);
    const int nbPrep = BH * 64 + BH * 32 + S_LEN;   // K-cvt + V-transpose + mask (4x c-split)
    prep<<<dim3(nbPrep), 256, 0, stream>>>(K, V, mask, Kws, Vws, Mbits, BH);
    fa_fwd10<<<dim3((S_LEN / 64) * BH), 256, 0, stream>>>(Q, Kws, Vws, Mbits, Out);
  } else {
    fa_fwd<<<dim3(S_LEN / 64, BH), 256, 0, stream>>>(Q, K, V, mask, Out);
  }
}